// Round 21
// baseline (190.649 us; speedup 1.0000x reference)
//
#include <hip/hip_runtime.h>
#include <math.h>

typedef __attribute__((ext_vector_type(8))) short bf16x8;
typedef __attribute__((ext_vector_type(4))) float f32x4;
typedef __attribute__((ext_vector_type(4))) unsigned short u16x4;

#define B_    2
#define T_    2048
#define DIM_  1024
#define H_    16
#define KV_   4
#define HD_   64

// 1/sqrt(HD) * log2(e): folded into Q at projection time -> S is exp2-domain
#define QSCALE 0.1803368801111437f
// fixed softmax exponent offset (shift-invariance): P = exp2(s - SOFF)
#define SOFF  24.0f

static __device__ __forceinline__ unsigned short f2bf(float f) {
    union { float f; unsigned int u; } v; v.f = f;
    unsigned int r = v.u + 0x7fff + ((v.u >> 16) & 1);   // RNE
    return (unsigned short)(r >> 16);
}

// pack two f32 -> two bf16 (round-half-up)
static __device__ __forceinline__ unsigned int pkbf(float lo, float hi) {
    union { float f; unsigned int u; } a, b; a.f = lo; b.f = hi;
    return ((a.u + 0x8000u) >> 16) | ((b.u + 0x8000u) & 0xffff0000u);
}

static __device__ __forceinline__ void gload16(const void* g, void* l) {
    __builtin_amdgcn_global_load_lds(
        (const __attribute__((address_space(1))) unsigned int*)g,
        (__attribute__((address_space(3))) unsigned int*)l, 16, 0, 0);
}

#define MFMA16(a, b, c) __builtin_amdgcn_mfma_f32_16x16x32_bf16(a, b, c, 0, 0, 0)

// Workspace (unsigned short elements):
#define XB_OFF   0u
#define WT_OFF   4194304u
#define WOT_OFF  5767168u
#define QB_OFF   6815744u
#define KB_OFF   11010048u
#define VTB_OFF  12058624u
#define AB_OFF   13107200u
#define MB_OFF   17301504u   // f32[4096] mask bias (16 KB)

// ---------------------------------------------------------------------------
// Fused pre-pass: x->bf16, 4 weight transposes, mask->additive-bias.
// ---------------------------------------------------------------------------
static __device__ __forceinline__ void wtrans_body(
    const float* __restrict__ W, unsigned short* __restrict__ Wt, int N,
    int n0, int k0, int tid, float (*Ts)[65])
{
    const int r = tid >> 4, c4 = (tid & 15) * 4;
    #pragma unroll
    for (int i = 0; i < 4; ++i) {
        float4 v = *(const float4*)&W[(size_t)(k0 + r + 16 * i) * N + n0 + c4];
        Ts[r + 16 * i][c4 + 0] = v.x; Ts[r + 16 * i][c4 + 1] = v.y;
        Ts[r + 16 * i][c4 + 2] = v.z; Ts[r + 16 * i][c4 + 3] = v.w;
    }
    __syncthreads();
    const int rn = tid >> 3, ck = (tid & 7) * 8;
    #pragma unroll
    for (int i = 0; i < 2; ++i) {
        int n = rn + 32 * i;
        unsigned short u[8];
        #pragma unroll
        for (int e = 0; e < 8; ++e) u[e] = f2bf(Ts[ck + e][n]);
        *(bf16x8*)&Wt[(size_t)(n0 + n) * 1024 + k0 + ck] = *(bf16x8*)u;
    }
}

__global__ __launch_bounds__(256) void prepass_kernel(
    const float* __restrict__ x,
    const float* __restrict__ Wq, const float* __restrict__ Wk,
    const float* __restrict__ Wv, const float* __restrict__ Wo,
    const float* __restrict__ maskp,
    unsigned short* __restrict__ xb, unsigned short* __restrict__ Wt,
    unsigned short* __restrict__ Wot, float* __restrict__ mbias)
{
    __shared__ float Ts[64][65];
    const int blk = blockIdx.x, tid = threadIdx.x;

    if (blk < 2048) {                      // x f32 -> bf16
        const size_t i = ((size_t)blk * 256 + tid) * 8;
        float4 a = *(const float4*)&x[i];
        float4 b = *(const float4*)&x[i + 4];
        unsigned short u[8] = {f2bf(a.x), f2bf(a.y), f2bf(a.z), f2bf(a.w),
                               f2bf(b.x), f2bf(b.y), f2bf(b.z), f2bf(b.w)};
        *(bf16x8*)&xb[i] = *(bf16x8*)u;
    } else if (blk < 2304) {               // Wq^T
        const int sb = blk - 2048;
        wtrans_body(Wq, Wt, 1024, (sb & 15) * 64, (sb >> 4) * 64, tid, Ts);
    } else if (blk < 2368) {               // Wk^T
        const int sb = blk - 2304;
        wtrans_body(Wk, Wt + 1024u * 1024u, 256, (sb & 3) * 64, (sb >> 2) * 64,
                    tid, Ts);
    } else if (blk < 2432) {               // Wv^T
        const int sb = blk - 2368;
        wtrans_body(Wv, Wt + 1280u * 1024u, 256, (sb & 3) * 64, (sb >> 2) * 64,
                    tid, Ts);
    } else if (blk < 2688) {               // Wo^T
        const int sb = blk - 2432;
        wtrans_body(Wo, Wot, 1024, (sb & 15) * 64, (sb >> 4) * 64, tid, Ts);
    } else {                               // mask -> additive bias (-SOFF/-1e30)
        #pragma unroll
        for (int e = 0; e < 4; ++e) {
            const int i = tid * 16 + e * 4;
            f32x4 mv = *(const f32x4*)&maskp[i];
            f32x4 bv;
            #pragma unroll
            for (int j = 0; j < 4; ++j) bv[j] = mv[j] > 0.f ? -SOFF : -1e30f;
            *(f32x4*)&mbias[i] = bv;
        }
    }
}

// ---------------------------------------------------------------------------
// Kernel 1: QKV bf16 MFMA GEMM + RoPE epilogue.  64x128 tile, BK=64,
// grid (12,64) = 768 blocks, 4 waves: wave = 32 rows x 64 cols.
// ---------------------------------------------------------------------------
__global__ __launch_bounds__(256) void qkv_mfma_kernel(
    const unsigned short* __restrict__ xb, const unsigned short* __restrict__ Wt,
    const float* __restrict__ sinp, const float* __restrict__ cosp,
    unsigned short* __restrict__ Qw, unsigned short* __restrict__ Kw,
    unsigned short* __restrict__ Vtw)
{
    __shared__ __align__(16) unsigned char As[8192];    // [64 m][128B], swizzled
    __shared__ __align__(16) unsigned char Bs[16384];   // [128 n][128B]

    const int tid = threadIdx.x, lane = tid & 63, w = tid >> 6;
    const int lr = lane & 15, lg = lane >> 4;
    const int wm = w >> 1, wn = w & 1;
    const int bn = blockIdx.x, bm = blockIdx.y;
    const int m0 = bm * 64, n0 = bn * 128;

    const int chunkR = lane >> 3;
    const int srcOff = 8 * ((lane & 7) ^ chunkR);

    f32x4 acc[2][4] = {};

    for (int k0 = 0; k0 < 1024; k0 += 64) {
        __syncthreads();
        #pragma unroll
        for (int i = 0; i < 6; ++i) {
            const int c = w * 6 + i;
            if (c < 8) {
                const int row = c * 8 + chunkR;
                gload16(xb + (size_t)(m0 + row) * 1024 + k0 + srcOff, As + c * 1024);
            } else {
                const int row = (c - 8) * 8 + chunkR;
                gload16(Wt + (size_t)(n0 + row) * 1024 + k0 + srcOff,
                        Bs + (c - 8) * 1024);
            }
        }
        __syncthreads();
        #pragma unroll
        for (int kk = 0; kk < 2; ++kk) {
            bf16x8 af[2], bfr[4];
            #pragma unroll
            for (int mf = 0; mf < 2; ++mf) {
                const int row = wm * 32 + mf * 16 + lr;
                af[mf] = *(const bf16x8*)(As + row * 128 +
                          ((kk * 64 + lg * 16) ^ ((row & 7) << 4)));
            }
            #pragma unroll
            for (int nf = 0; nf < 4; ++nf) {
                const int row = wn * 64 + nf * 16 + lr;
                bfr[nf] = *(const bf16x8*)(Bs + row * 128 +
                          ((kk * 64 + lg * 16) ^ ((row & 7) << 4)));
            }
            #pragma unroll
            for (int mf = 0; mf < 2; ++mf)
                #pragma unroll
                for (int nf = 0; nf < 4; ++nf)
                    acc[mf][nf] = MFMA16(af[mf], bfr[nf], acc[mf][nf]);
        }
    }

    const float rsign = (lane & 1) ? 1.f : -1.f;
    #pragma unroll
    for (int nf = 0; nf < 4; ++nf) {
        const int col = n0 + wn * 64 + nf * 16 + lr;
        #pragma unroll
        for (int mf = 0; mf < 2; ++mf) {
            const int mrow = m0 + wm * 32 + mf * 16 + lg * 4;
            const int b = mrow >> 11;
            const int t0 = mrow & 2047;
            if (col < 1280) {   // Q or K: RoPE
                const int d = col & 63;
                #pragma unroll
                for (int r = 0; r < 4; ++r) {
                    float val = acc[mf][nf][r];
                    float partner = __shfl_xor(val, 1);
                    const int t = t0 + r;
                    float cs = cosp[t * 64 + d], sn = sinp[t * 64 + d];
                    float rv = val * cs + rsign * partner * sn;
                    if (col < 1024) {
                        const int h = col >> 6;
                        Qw[(((size_t)b * H_ + h) * T_ + t) * 64 + d] =
                            f2bf(rv * QSCALE);
                    } else {
                        const int kv = (col - 1024) >> 6;
                        char* krow = (char*)Kw +
                            ((((size_t)b * KV_ + kv) * T_ + t) << 7);
                        *(unsigned short*)(krow + ((2 * d) ^ ((t & 7) << 4))) =
                            f2bf(rv);
                    }
                }
            } else {            // V: transposed swizzled store, 4 t packed
                const int cv = col - 1280, kv = cv >> 6, d = cv & 63;
                unsigned short u[4];
                #pragma unroll
                for (int r = 0; r < 4; ++r) u[r] = f2bf(acc[mf][nf][r]);
                char* vrow = (char*)Vtw +
                    ((((size_t)b * KV_ + kv) * 64 + d) * (size_t)T_ * 2);
                *(u16x4*)(vrow + ((2 * t0) ^ ((d & 7) << 4))) = *(u16x4*)u;
            }
        }
    }
}

// ---------------------------------------------------------------------------
// Kernel 2: causal GQA flash attention, SPLIT-K + TWO q-tiles per wave (ILP).
// Block = 8 waves = 2 key-groups x 4 q-chunks; q-tiles qa=2pg, qb=2pg+1.
// Group A keys [0,pg+1), B [pg+1,2pg+2) -- equal counts. Each wave runs two
// independent QK->softmax->PV chains (shared kb loads, shared bias), halving
// barriers/staging per unit work and doubling in-wave ILP. Fixed-offset exp2
// softmax. Grid = B*H*16 = 512 blocks, longest-first. LDS 50KB.
// ---------------------------------------------------------------------------
__global__ __launch_bounds__(512, 4) void attn_kernel(
    const unsigned short* __restrict__ Qg, const unsigned short* __restrict__ Kg,
    const unsigned short* __restrict__ Vtg, const float* __restrict__ mbias,
    unsigned short* __restrict__ attn_out)
{
    __shared__ __align__(16) unsigned char Kl[2][8192];   // per-group [key][d]; reused oa
    __shared__ __align__(16) unsigned char Vl[2][8192];   // per-group [d][key]; reused ob
    __shared__ __align__(16) unsigned char Pl[8][2048];   // per-wave P^T
    __shared__ float Lb[512];                             // B partial la,lb

    const int tid  = threadIdx.x;
    const int lane = tid & 63;
    const int w    = tid >> 6;             // 0..7
    const int grp  = w >> 2;               // key-group
    const int wq   = w & 3;                // q-chunk (16 rows)
    const int lr   = lane & 15;
    const int lg   = lane >> 4;

    const int bi   = blockIdx.x;
    const int pg   = 15 - (bi >> 5);       // pair index, longest-first
    const int bh   = bi & 31;
    const int h    = bh & 15;
    const int b    = bh >> 4;
    const int kvh  = h >> 2;
    const int qa_t = 2 * pg;               // q-tile indices
    const int qb_t = 2 * pg + 1;
    const int qra  = qa_t * 64 + wq * 16 + lr;
    const int qrb  = qra + 64;

    const int iters = pg + 1;              // tiles per group (equal)

    const char* Kb = (const char*)(Kg  + ((size_t)b * KV_ + kvh) * T_ * HD_);
    const char* Vb = (const char*)(Vtg + ((size_t)b * KV_ + kvh) * HD_ * T_);
    const float* brow = mbias + b * T_;

    const int sr  = lane >> 3;
    const int scb = (lane & 7) * 16;
    unsigned char* Pw = &Pl[w][0];

    const unsigned short* Qba = Qg + (((size_t)b * H_ + h) * T_ + qra) * HD_;
    const unsigned short* Qbb = Qg + (((size_t)b * H_ + h) * T_ + qrb) * HD_;
    const bf16x8 qfa0 = *(const bf16x8*)(Qba + lg * 8);
    const bf16x8 qfa1 = *(const bf16x8*)(Qba + 32 + lg * 8);
    const bf16x8 qfb0 = *(const bf16x8*)(Qbb + lg * 8);
    const bf16x8 qfb1 = *(const bf16x8*)(Qbb + 32 + lg * 8);

    f32x4 oa[4] = {}, ob[4] = {};
    float la = 0.f, lb = 0.f;

    for (int it = 0; it < iters; ++it) {
        const int ktg = grp ? (pg + 1 + it) : it;
        const int k0  = ktg * 64;

        #pragma unroll
        for (int i = 0; i < 2; ++i) {
            const int rb  = wq * 2 + i;
            const int row = rb * 8 + sr;
            gload16(Kb + (size_t)(k0 + row) * 128 + scb, &Kl[grp][rb * 1024]);
            gload16(Vb + (size_t)row * 4096 + 2 * k0 + scb, &Vl[grp][rb * 1024]);
        }
        __syncthreads();   // staging landed

        const unsigned char* Kc = Kl[grp];
        const unsigned char* Vc = Vl[grp];

        // shared additive mask bias (keys only)
        f32x4 bv[4];
        #pragma unroll
        for (int n = 0; n < 4; ++n)
            bv[n] = *(const f32x4*)&brow[k0 + 16 * n + 4 * lg];

        // QK^T for BOTH q-tiles (shared kb loads, 2 independent MFMA chains)
        f32x4 sa[4] = {}, sb[4] = {};
        __builtin_amdgcn_s_setprio(1);
        #pragma unroll
        for (int n = 0; n < 4; ++n) {
            const int key = 16 * n + lr;
            #pragma unroll
            for (int ks = 0; ks < 2; ++ks) {
                bf16x8 kb = *(const bf16x8*)(Kc +
                    ((key * 128 + 64 * ks + lg * 16) ^ ((key & 7) << 4)));
                sa[n] = MFMA16(kb, ks == 0 ? qfa0 : qfa1, sa[n]);
                sb[n] = MFMA16(kb, ks == 0 ? qfb0 : qfb1, sb[n]);
            }
        }
        __builtin_amdgcn_s_setprio(0);

        // bias + causal (qa: when ktg >= qa_t; qb: only at ktg == qb_t)
        if (ktg >= qa_t) {
            #pragma unroll
            for (int n = 0; n < 4; ++n)
                #pragma unroll
                for (int r = 0; r < 4; ++r) {
                    const int keyg = k0 + 16 * n + 4 * lg + r;
                    sa[n][r] = (keyg <= qra) ? sa[n][r] + bv[n][r] : -1e30f;
                }
        } else {
            #pragma unroll
            for (int n = 0; n < 4; ++n)
                #pragma unroll
                for (int r = 0; r < 4; ++r) sa[n][r] += bv[n][r];
        }
        if (ktg == qb_t) {
            #pragma unroll
            for (int n = 0; n < 4; ++n)
                #pragma unroll
                for (int r = 0; r < 4; ++r) {
                    const int keyg = k0 + 16 * n + 4 * lg + r;
                    sb[n][r] = (keyg <= qrb) ? sb[n][r] + bv[n][r] : -1e30f;
                }
        } else {
            #pragma unroll
            for (int n = 0; n < 4; ++n)
                #pragma unroll
                for (int r = 0; r < 4; ++r) sb[n][r] += bv[n][r];
        }
        #pragma unroll
        for (int n = 0; n < 4; ++n)
            #pragma unroll
            for (int r = 0; r < 4; ++r) {
                sa[n][r] = exp2f(sa[n][r]);
                sb[n][r] = exp2f(sb[n][r]);
            }

        // l accumulation (per-lane; reduced in epilogue)
        float ta[4], tb[4];
        #pragma unroll
        for (int n = 0; n < 4; ++n) {
            ta[n] = (sa[n][0] + sa[n][1]) + (sa[n][2] + sa[n][3]);
            tb[n] = (sb[n][0] + sb[n][1]) + (sb[n][2] + sb[n][3]);
        }
        la += (ta[0] + ta[1]) + (ta[2] + ta[3]);
        lb += (tb[0] + tb[1]) + (tb[2] + tb[3]);

        // qa: P pack -> LDS -> PV
        #pragma unroll
        for (int n = 0; n < 4; ++n) {
            uint2 wv;
            wv.x = pkbf(sa[n][0], sa[n][1]);
            wv.y = pkbf(sa[n][2], sa[n][3]);
            *(uint2*)(Pw + ((lr * 128 + 32 * n + 8 * lg) ^ ((lr & 7) << 4))) = wv;
        }
        {
            bf16x8 pa0 = *(const bf16x8*)(Pw + ((lr * 128 +      lg * 16) ^ ((lr & 7) << 4)));
            bf16x8 pa1 = *(const bf16x8*)(Pw + ((lr * 128 + 64 + lg * 16) ^ ((lr & 7) << 4)));
            __builtin_amdgcn_s_setprio(1);
            #pragma unroll
            for (int n = 0; n < 4; ++n) {
                const int d = 16 * n + lr;
                #pragma unroll
                for (int ks = 0; ks < 2; ++ks) {
                    bf16x8 vb = *(const bf16x8*)(Vc +
                        ((d * 128 + 64 * ks + lg * 16) ^ ((d & 7) << 4)));
                    oa[n] = MFMA16(vb, ks == 0 ? pa0 : pa1, oa[n]);
                }
            }
            __builtin_amdgcn_s_setprio(0);
        }

        // qb: P pack -> LDS (reuse, same-wave in-order DS) -> PV
        #pragma unroll
        for (int n = 0; n < 4; ++n) {
            uint2 wv;
            wv.x = pkbf(sb[n][0], sb[n][1]);
            wv.y = pkbf(sb[n][2], sb[n][3]);
            *(uint2*)(Pw + ((lr * 128 + 32 * n + 8 * lg) ^ ((lr & 7) << 4))) = wv;
        }
        {
            bf16x8 pb0 = *(const bf16x8*)(Pw + ((lr * 128 +      lg * 16) ^ ((lr & 7) << 4)));
            bf16x8 pb1 = *(const bf16x8*)(Pw + ((lr * 128 + 64 + lg * 16) ^ ((lr & 7) << 4)));
            __builtin_amdgcn_s_setprio(1);
            #pragma unroll
            for (int n = 0; n < 4; ++n) {
                const int d = 16 * n + lr;
                #pragma unroll
                for (int ks = 0; ks < 2; ++ks) {
                    bf16x8 vb = *(const bf16x8*)(Vc +
                        ((d * 128 + 64 * ks + lg * 16) ^ ((d & 7) << 4)));
                    ob[n] = MFMA16(vb, ks == 0 ? pb0 : pb1, ob[n]);
                }
            }
            __builtin_amdgcn_s_setprio(0);
        }

        __syncthreads();   // all reads done before next tile's staging
    }

    // ---- split-K merge: B publishes (oa,ob,la,lb) via retired K/V LDS ----
    const int slot = wq * 64 + lane;
    if (grp) {
        float* pa = (float*)Kl;
        float* pb = (float*)Vl;
        #pragma unroll
        for (int n = 0; n < 4; ++n) {
            *(f32x4*)&pa[slot * 16 + n * 4] = oa[n];
            *(f32x4*)&pb[slot * 16 + n * 4] = ob[n];
        }
        Lb[slot]       = la;
        Lb[256 + slot] = lb;
    }
    __syncthreads();
    if (!grp) {
        const float* pa = (const float*)Kl;
        const float* pb = (const float*)Vl;
        #pragma unroll
        for (int n = 0; n < 4; ++n) {
            oa[n] += *(const f32x4*)&pa[slot * 16 + n * 4];
            ob[n] += *(const f32x4*)&pb[slot * 16 + n * 4];
        }
        float lfa = la + Lb[slot];
        float lfb = lb + Lb[256 + slot];
        lfa += __shfl_xor(lfa, 16);
        lfa += __shfl_xor(lfa, 32);
        lfb += __shfl_xor(lfb, 16);
        lfb += __shfl_xor(lfb, 32);
        const float lia = 1.f / lfa;
        const float lib = 1.f / lfb;
        unsigned short* ra = attn_out + ((size_t)b * T_ + qra) * DIM_ + h * HD_;
        unsigned short* rb = attn_out + ((size_t)b * T_ + qrb) * DIM_ + h * HD_;
        #pragma unroll
        for (int n = 0; n < 4; ++n) {
            unsigned short ua[4], ub[4];
            #pragma unroll
            for (int r = 0; r < 4; ++r) {
                ua[r] = f2bf(oa[n][r] * lia);
                ub[r] = f2bf(ob[n][r] * lib);
            }
            *(u16x4*)&ra[16 * n + 4 * lg] = *(u16x4*)ua;
            *(u16x4*)&rb[16 * n + 4 * lg] = *(u16x4*)ub;
        }
    }
}

// ---------------------------------------------------------------------------
// Kernel 3: output projection bf16 MFMA. 64x128 tile, grid (8,64) = 512 blocks.
// ---------------------------------------------------------------------------
__global__ __launch_bounds__(256) void outproj_mfma_kernel(
    const unsigned short* __restrict__ Ab, const unsigned short* __restrict__ Wot,
    float* __restrict__ out)
{
    __shared__ __align__(16) unsigned char As[8192];
    __shared__ __align__(16) unsigned char Bs[16384];

    const int tid = threadIdx.x, lane = tid & 63, w = tid >> 6;
    const int lr = lane & 15, lg = lane >> 4;
    const int wm = w >> 1, wn = w & 1;
    const int bn = blockIdx.x, bm = blockIdx.y;
    const int m0 = bm * 64, n0 = bn * 128;

    const int chunkR = lane >> 3;
    const int srcOff = 8 * ((lane & 7) ^ chunkR);

    f32x4 acc[2][4] = {};

    for (int k0 = 0; k0 < 1024; k0 += 64) {
        __syncthreads();
        #pragma unroll
        for (int i = 0; i < 6; ++i) {
            const int c = w * 6 + i;
            if (c < 8) {
                const int row = c * 8 + chunkR;
                gload16(Ab + (size_t)(m0 + row) * 1024 + k0 + srcOff, As + c * 1024);
            } else {
                const int row = (c - 8) * 8 + chunkR;
                gload16(Wot + (size_t)(n0 + row) * 1024 + k0 + srcOff,
                        Bs + (c - 8) * 1024);
            }
        }
        __syncthreads();
        #pragma unroll
        for (int kk = 0; kk < 2; ++kk) {
            bf16x8 af[2], bfr[4];
            #pragma unroll
            for (int mf = 0; mf < 2; ++mf) {
                const int row = wm * 32 + mf * 16 + lr;
                af[mf] = *(const bf16x8*)(As + row * 128 +
                          ((kk * 64 + lg * 16) ^ ((row & 7) << 4)));
            }
            #pragma unroll
            for (int nf = 0; nf < 4; ++nf) {
                const int row = wn * 64 + nf * 16 + lr;
                bfr[nf] = *(const bf16x8*)(Bs + row * 128 +
                          ((kk * 64 + lg * 16) ^ ((row & 7) << 4)));
            }
            #pragma unroll
            for (int mf = 0; mf < 2; ++mf)
                #pragma unroll
                for (int nf = 0; nf < 4; ++nf)
                    acc[mf][nf] = MFMA16(af[mf], bfr[nf], acc[mf][nf]);
        }
    }

    #pragma unroll
    for (int nf = 0; nf < 4; ++nf) {
        const int col = n0 + wn * 64 + nf * 16 + lr;
        #pragma unroll
        for (int mf = 0; mf < 2; ++mf) {
            const int mrow = m0 + wm * 32 + mf * 16 + lg * 4;
            #pragma unroll
            for (int r = 0; r < 4; ++r)
                out[(size_t)(mrow + r) * 1024 + col] = acc[mf][nf][r];
        }
    }
}

// ---------------------------------------------------------------------------
extern "C" void kernel_launch(void* const* d_in, const int* in_sizes, int n_in,
                              void* d_out, int out_size, void* d_ws, size_t ws_size,
                              hipStream_t stream)
{
    const float* x     = (const float*)d_in[0];
    const float* sinp  = (const float*)d_in[1];
    const float* cosp  = (const float*)d_in[2];
    const float* maskp = (const float*)d_in[3];
    const float* Wq    = (const float*)d_in[4];
    const float* Wk    = (const float*)d_in[5];
    const float* Wv    = (const float*)d_in[6];
    const float* Wo    = (const float*)d_in[7];

    unsigned short* wsb = (unsigned short*)d_ws;
    unsigned short* xb  = wsb + XB_OFF;
    unsigned short* Wt  = wsb + WT_OFF;
    unsigned short* Wot = wsb + WOT_OFF;
    unsigned short* Qw  = wsb + QB_OFF;
    unsigned short* Kw  = wsb + KB_OFF;
    unsigned short* Vtw = wsb + VTB_OFF;
    unsigned short* Ab  = wsb + AB_OFF;
    float* mbias        = (float*)(wsb + MB_OFF);
    float* out = (float*)d_out;

    prepass_kernel<<<2689, 256, 0, stream>>>(x, Wq, Wk, Wv, Wo, maskp,
                                             xb, Wt, Wot, mbias);
    qkv_mfma_kernel<<<dim3(12, 64), 256, 0, stream>>>(xb, Wt, sinp, cosp,
                                                      Qw, Kw, Vtw);
    attn_kernel<<<dim3(512), 512, 0, stream>>>(
        Qw, Kw, Vtw, mbias, Ab);
    outproj_mfma_kernel<<<dim3(8, 64), 256, 0, stream>>>(Ab, Wot, out);
}

// Round 22
// 103.662 us; speedup vs baseline: 1.8391x; 1.8391x over previous
//
#include <hip/hip_runtime.h>
#include <math.h>

typedef __attribute__((ext_vector_type(8))) short bf16x8;
typedef __attribute__((ext_vector_type(4))) float f32x4;
typedef __attribute__((ext_vector_type(4))) unsigned short u16x4;

#define B_    2
#define T_    2048
#define DIM_  1024
#define H_    16
#define KV_   4
#define HD_   64

// 1/sqrt(HD) * log2(e): folded into Q at projection time -> S is exp2-domain
#define QSCALE 0.1803368801111437f
// fixed softmax exponent offset (shift-invariance): P = exp2(s - SOFF)
#define SOFF  24.0f

static __device__ __forceinline__ unsigned short f2bf(float f) {
    union { float f; unsigned int u; } v; v.f = f;
    unsigned int r = v.u + 0x7fff + ((v.u >> 16) & 1);   // RNE
    return (unsigned short)(r >> 16);
}

// pack two f32 -> two bf16 (round-half-up)
static __device__ __forceinline__ unsigned int pkbf(float lo, float hi) {
    union { float f; unsigned int u; } a, b; a.f = lo; b.f = hi;
    return ((a.u + 0x8000u) >> 16) | ((b.u + 0x8000u) & 0xffff0000u);
}

static __device__ __forceinline__ void gload16(const void* g, void* l) {
    __builtin_amdgcn_global_load_lds(
        (const __attribute__((address_space(1))) unsigned int*)g,
        (__attribute__((address_space(3))) unsigned int*)l, 16, 0, 0);
}

#define MFMA16(a, b, c) __builtin_amdgcn_mfma_f32_16x16x32_bf16(a, b, c, 0, 0, 0)

// Workspace (unsigned short elements):
#define XB_OFF   0u
#define WT_OFF   4194304u
#define WOT_OFF  5767168u
#define QB_OFF   6815744u
#define KB_OFF   11010048u
#define VTB_OFF  12058624u
#define AB_OFF   13107200u
#define MB_OFF   17301504u   // f32[4096] mask bias (16 KB)

// ---------------------------------------------------------------------------
// Fused pre-pass: x->bf16, 4 weight transposes, mask->additive-bias.
// ---------------------------------------------------------------------------
static __device__ __forceinline__ void wtrans_body(
    const float* __restrict__ W, unsigned short* __restrict__ Wt, int N,
    int n0, int k0, int tid, float (*Ts)[65])
{
    const int r = tid >> 4, c4 = (tid & 15) * 4;
    #pragma unroll
    for (int i = 0; i < 4; ++i) {
        float4 v = *(const float4*)&W[(size_t)(k0 + r + 16 * i) * N + n0 + c4];
        Ts[r + 16 * i][c4 + 0] = v.x; Ts[r + 16 * i][c4 + 1] = v.y;
        Ts[r + 16 * i][c4 + 2] = v.z; Ts[r + 16 * i][c4 + 3] = v.w;
    }
    __syncthreads();
    const int rn = tid >> 3, ck = (tid & 7) * 8;
    #pragma unroll
    for (int i = 0; i < 2; ++i) {
        int n = rn + 32 * i;
        unsigned short u[8];
        #pragma unroll
        for (int e = 0; e < 8; ++e) u[e] = f2bf(Ts[ck + e][n]);
        *(bf16x8*)&Wt[(size_t)(n0 + n) * 1024 + k0 + ck] = *(bf16x8*)u;
    }
}

__global__ __launch_bounds__(256) void prepass_kernel(
    const float* __restrict__ x,
    const float* __restrict__ Wq, const float* __restrict__ Wk,
    const float* __restrict__ Wv, const float* __restrict__ Wo,
    const float* __restrict__ maskp,
    unsigned short* __restrict__ xb, unsigned short* __restrict__ Wt,
    unsigned short* __restrict__ Wot, float* __restrict__ mbias)
{
    __shared__ float Ts[64][65];
    const int blk = blockIdx.x, tid = threadIdx.x;

    if (blk < 2048) {                      // x f32 -> bf16
        const size_t i = ((size_t)blk * 256 + tid) * 8;
        float4 a = *(const float4*)&x[i];
        float4 b = *(const float4*)&x[i + 4];
        unsigned short u[8] = {f2bf(a.x), f2bf(a.y), f2bf(a.z), f2bf(a.w),
                               f2bf(b.x), f2bf(b.y), f2bf(b.z), f2bf(b.w)};
        *(bf16x8*)&xb[i] = *(bf16x8*)u;
    } else if (blk < 2304) {               // Wq^T
        const int sb = blk - 2048;
        wtrans_body(Wq, Wt, 1024, (sb & 15) * 64, (sb >> 4) * 64, tid, Ts);
    } else if (blk < 2368) {               // Wk^T
        const int sb = blk - 2304;
        wtrans_body(Wk, Wt + 1024u * 1024u, 256, (sb & 3) * 64, (sb >> 2) * 64,
                    tid, Ts);
    } else if (blk < 2432) {               // Wv^T
        const int sb = blk - 2368;
        wtrans_body(Wv, Wt + 1280u * 1024u, 256, (sb & 3) * 64, (sb >> 2) * 64,
                    tid, Ts);
    } else if (blk < 2688) {               // Wo^T
        const int sb = blk - 2432;
        wtrans_body(Wo, Wot, 1024, (sb & 15) * 64, (sb >> 4) * 64, tid, Ts);
    } else {                               // mask -> additive bias (-SOFF/-1e30)
        #pragma unroll
        for (int e = 0; e < 4; ++e) {
            const int i = tid * 16 + e * 4;
            f32x4 mv = *(const f32x4*)&maskp[i];
            f32x4 bv;
            #pragma unroll
            for (int j = 0; j < 4; ++j) bv[j] = mv[j] > 0.f ? -SOFF : -1e30f;
            *(f32x4*)&mbias[i] = bv;
        }
    }
}

// ---------------------------------------------------------------------------
// Kernel 1: QKV bf16 MFMA GEMM + RoPE epilogue.  64x128 tile, BK=64,
// grid (12,64) = 768 blocks, 4 waves: wave = 32 rows x 64 cols.
// ---------------------------------------------------------------------------
__global__ __launch_bounds__(256) void qkv_mfma_kernel(
    const unsigned short* __restrict__ xb, const unsigned short* __restrict__ Wt,
    const float* __restrict__ sinp, const float* __restrict__ cosp,
    unsigned short* __restrict__ Qw, unsigned short* __restrict__ Kw,
    unsigned short* __restrict__ Vtw)
{
    __shared__ __align__(16) unsigned char As[8192];    // [64 m][128B], swizzled
    __shared__ __align__(16) unsigned char Bs[16384];   // [128 n][128B]

    const int tid = threadIdx.x, lane = tid & 63, w = tid >> 6;
    const int lr = lane & 15, lg = lane >> 4;
    const int wm = w >> 1, wn = w & 1;
    const int bn = blockIdx.x, bm = blockIdx.y;
    const int m0 = bm * 64, n0 = bn * 128;

    const int chunkR = lane >> 3;
    const int srcOff = 8 * ((lane & 7) ^ chunkR);

    f32x4 acc[2][4] = {};

    for (int k0 = 0; k0 < 1024; k0 += 64) {
        __syncthreads();
        #pragma unroll
        for (int i = 0; i < 6; ++i) {
            const int c = w * 6 + i;
            if (c < 8) {
                const int row = c * 8 + chunkR;
                gload16(xb + (size_t)(m0 + row) * 1024 + k0 + srcOff, As + c * 1024);
            } else {
                const int row = (c - 8) * 8 + chunkR;
                gload16(Wt + (size_t)(n0 + row) * 1024 + k0 + srcOff,
                        Bs + (c - 8) * 1024);
            }
        }
        __syncthreads();
        #pragma unroll
        for (int kk = 0; kk < 2; ++kk) {
            bf16x8 af[2], bfr[4];
            #pragma unroll
            for (int mf = 0; mf < 2; ++mf) {
                const int row = wm * 32 + mf * 16 + lr;
                af[mf] = *(const bf16x8*)(As + row * 128 +
                          ((kk * 64 + lg * 16) ^ ((row & 7) << 4)));
            }
            #pragma unroll
            for (int nf = 0; nf < 4; ++nf) {
                const int row = wn * 64 + nf * 16 + lr;
                bfr[nf] = *(const bf16x8*)(Bs + row * 128 +
                          ((kk * 64 + lg * 16) ^ ((row & 7) << 4)));
            }
            #pragma unroll
            for (int mf = 0; mf < 2; ++mf)
                #pragma unroll
                for (int nf = 0; nf < 4; ++nf)
                    acc[mf][nf] = MFMA16(af[mf], bfr[nf], acc[mf][nf]);
        }
    }

    const float rsign = (lane & 1) ? 1.f : -1.f;
    #pragma unroll
    for (int nf = 0; nf < 4; ++nf) {
        const int col = n0 + wn * 64 + nf * 16 + lr;
        #pragma unroll
        for (int mf = 0; mf < 2; ++mf) {
            const int mrow = m0 + wm * 32 + mf * 16 + lg * 4;
            const int b = mrow >> 11;
            const int t0 = mrow & 2047;
            if (col < 1280) {   // Q or K: RoPE
                const int d = col & 63;
                #pragma unroll
                for (int r = 0; r < 4; ++r) {
                    float val = acc[mf][nf][r];
                    float partner = __shfl_xor(val, 1);
                    const int t = t0 + r;
                    float cs = cosp[t * 64 + d], sn = sinp[t * 64 + d];
                    float rv = val * cs + rsign * partner * sn;
                    if (col < 1024) {
                        const int h = col >> 6;
                        Qw[(((size_t)b * H_ + h) * T_ + t) * 64 + d] =
                            f2bf(rv * QSCALE);
                    } else {
                        const int kv = (col - 1024) >> 6;
                        char* krow = (char*)Kw +
                            ((((size_t)b * KV_ + kv) * T_ + t) << 7);
                        *(unsigned short*)(krow + ((2 * d) ^ ((t & 7) << 4))) =
                            f2bf(rv);
                    }
                }
            } else {            // V: transposed swizzled store, 4 t packed
                const int cv = col - 1280, kv = cv >> 6, d = cv & 63;
                unsigned short u[4];
                #pragma unroll
                for (int r = 0; r < 4; ++r) u[r] = f2bf(acc[mf][nf][r]);
                char* vrow = (char*)Vtw +
                    ((((size_t)b * KV_ + kv) * 64 + d) * (size_t)T_ * 2);
                *(u16x4*)(vrow + ((2 * t0) ^ ((d & 7) << 4))) = *(u16x4*)u;
            }
        }
    }
}

// ---------------------------------------------------------------------------
// Kernel 2: causal GQA flash attention, SPLIT-K, FIXED-OFFSET softmax.
// Block = 8 waves = 2 key-groups x 4 q-chunks(16 rows), one 64-row q-tile.
// Group A keys [0,mid), B [mid,nt) (owns diagonal). Fixed-offset exp2
// softmax; mask from precomputed additive bias; merge = plain adds.
// Grid = 1024 longest-first. __launch_bounds__(512,4): 128-VGPR budget.
// ---------------------------------------------------------------------------
__global__ __launch_bounds__(512, 4) void attn_kernel(
    const unsigned short* __restrict__ Qg, const unsigned short* __restrict__ Kg,
    const unsigned short* __restrict__ Vtg, const float* __restrict__ mbias,
    unsigned short* __restrict__ attn_out)
{
    __shared__ __align__(16) unsigned char Kl[2][8192];   // per-group [key][d]
    __shared__ __align__(16) unsigned char Vl[2][8192];   // per-group [d][key]
    __shared__ __align__(16) unsigned char Pl[16384];     // 8x2K P^T; reused OB
    __shared__ float Lb[256];                             // B partial l

    const int tid  = threadIdx.x;
    const int lane = tid & 63;
    const int w    = tid >> 6;             // 0..7
    const int grp  = w >> 2;               // 0 = keys [0,mid), 1 = [mid,nt)
    const int wq   = w & 3;
    const int lr   = lane & 15;
    const int lg   = lane >> 4;

    const int bi   = blockIdx.x;
    const int qt   = 31 - (bi >> 5);       // longest-first globally
    const int bh   = bi & 31;
    const int h    = bh & 15;
    const int b    = bh >> 4;
    const int kvh  = h >> 2;
    const int q0   = qt * 64;
    const int qrow = q0 + wq * 16 + lr;

    const int nt    = qt + 1;
    const int mid   = nt >> 1;             // A count
    const int iters = nt - mid;            // B count = ceil(nt/2) >= 1

    const char* Kb = (const char*)(Kg  + ((size_t)b * KV_ + kvh) * T_ * HD_);
    const char* Vb = (const char*)(Vtg + ((size_t)b * KV_ + kvh) * HD_ * T_);
    const float* brow = mbias + b * T_;

    const int sr  = lane >> 3;
    const int scb = (lane & 7) * 16;
    unsigned char* Pw = &Pl[w * 2048];

    const unsigned short* Qbase =
        Qg + (((size_t)b * H_ + h) * T_ + qrow) * HD_;
    const bf16x8 qf0 = *(const bf16x8*)(Qbase + lg * 8);
    const bf16x8 qf1 = *(const bf16x8*)(Qbase + 32 + lg * 8);

    f32x4 o[4] = {};
    float l = 0.f;

    for (int it = 0; it < iters; ++it) {
        const int ktg = grp ? (mid + it) : it;
        const bool active = grp || (it < mid);   // wave-uniform
        const int k0 = ktg * 64;

        if (active) {
            #pragma unroll
            for (int i = 0; i < 2; ++i) {
                const int rb  = wq * 2 + i;
                const int row = rb * 8 + sr;
                gload16(Kb + (size_t)(k0 + row) * 128 + scb, &Kl[grp][rb * 1024]);
                gload16(Vb + (size_t)row * 4096 + 2 * k0 + scb, &Vl[grp][rb * 1024]);
            }
        }
        __syncthreads();   // staging landed

        if (active) {
            const unsigned char* Kc = Kl[grp];
            const unsigned char* Vc = Vl[grp];

            // precomputed additive mask bias (-SOFF or -1e30)
            f32x4 bv[4];
            #pragma unroll
            for (int n = 0; n < 4; ++n)
                bv[n] = *(const f32x4*)&brow[k0 + 16 * n + 4 * lg];

            // QK^T transposed: s[n][r] = S[key=k0+16n+4lg+r][q=qrow]
            f32x4 s[4] = {};
            __builtin_amdgcn_s_setprio(1);
            #pragma unroll
            for (int n = 0; n < 4; ++n) {
                const int key = 16 * n + lr;
                #pragma unroll
                for (int ks = 0; ks < 2; ++ks) {
                    bf16x8 kb = *(const bf16x8*)(Kc +
                        ((key * 128 + 64 * ks + lg * 16) ^ ((key & 7) << 4)));
                    s[n] = MFMA16(kb, ks == 0 ? qf0 : qf1, s[n]);
                }
            }
            __builtin_amdgcn_s_setprio(0);

            // bias (+ causal on diagonal tile, group B only), then exp2
            if (ktg == qt) {
                #pragma unroll
                for (int n = 0; n < 4; ++n)
                    #pragma unroll
                    for (int r = 0; r < 4; ++r) {
                        const int keyg = k0 + 16 * n + 4 * lg + r;
                        s[n][r] = (keyg <= qrow) ? s[n][r] + bv[n][r] : -1e30f;
                    }
            } else {
                #pragma unroll
                for (int n = 0; n < 4; ++n)
                    #pragma unroll
                    for (int r = 0; r < 4; ++r) s[n][r] += bv[n][r];
            }
            #pragma unroll
            for (int n = 0; n < 4; ++n)
                #pragma unroll
                for (int r = 0; r < 4; ++r)
                    s[n][r] = exp2f(s[n][r]);

            // plain l accumulation (no cross-lane; reduced in epilogue)
            float tsum[4];
            #pragma unroll
            for (int n = 0; n < 4; ++n)
                tsum[n] = (s[n][0] + s[n][1]) + (s[n][2] + s[n][3]);
            l += (tsum[0] + tsum[1]) + (tsum[2] + tsum[3]);

            // P^T -> wave-private LDS (round-half-up pack)
            #pragma unroll
            for (int n = 0; n < 4; ++n) {
                uint2 wv;
                wv.x = pkbf(s[n][0], s[n][1]);
                wv.y = pkbf(s[n][2], s[n][3]);
                *(uint2*)(Pw + ((lr * 128 + 32 * n + 8 * lg) ^ ((lr & 7) << 4))) = wv;
            }
            bf16x8 pa0 = *(const bf16x8*)(Pw + ((lr * 128 +      lg * 16) ^ ((lr & 7) << 4)));
            bf16x8 pa1 = *(const bf16x8*)(Pw + ((lr * 128 + 64 + lg * 16) ^ ((lr & 7) << 4)));

            // PV transposed: o[n][r] = O[q=qrow][d=16n+4lg+r]
            __builtin_amdgcn_s_setprio(1);
            #pragma unroll
            for (int n = 0; n < 4; ++n) {
                const int d = 16 * n + lr;
                #pragma unroll
                for (int ks = 0; ks < 2; ++ks) {
                    bf16x8 vb = *(const bf16x8*)(Vc +
                        ((d * 128 + 64 * ks + lg * 16) ^ ((d & 7) << 4)));
                    o[n] = MFMA16(vb, ks == 0 ? pa0 : pa1, o[n]);
                }
            }
            __builtin_amdgcn_s_setprio(0);
        }

        __syncthreads();   // all reads done before next tile's staging
    }

    // ---- split-K merge: B publishes (o,l), A adds, row-reduces l, stores ----
    const int slot = wq * 64 + lane;
    if (grp) {
        float* ob = (float*)Pl;
        #pragma unroll
        for (int n = 0; n < 4; ++n)
            *(f32x4*)&ob[slot * 16 + n * 4] = o[n];
        Lb[slot] = l;
    }
    __syncthreads();
    if (!grp) {
        const float* ob = (const float*)Pl;
        #pragma unroll
        for (int n = 0; n < 4; ++n) {
            f32x4 obv = *(const f32x4*)&ob[slot * 16 + n * 4];
            o[n] += obv;
        }
        float lf = l + Lb[slot];
        lf += __shfl_xor(lf, 16);
        lf += __shfl_xor(lf, 32);
        const float linv = 1.f / lf;
        unsigned short* orow =
            attn_out + ((size_t)b * T_ + qrow) * DIM_ + h * HD_;
        #pragma unroll
        for (int n = 0; n < 4; ++n) {
            unsigned short u[4];
            #pragma unroll
            for (int r = 0; r < 4; ++r) u[r] = f2bf(o[n][r] * linv);
            *(u16x4*)&orow[16 * n + 4 * lg] = *(u16x4*)u;
        }
    }
}

// ---------------------------------------------------------------------------
// Kernel 3: output projection bf16 MFMA. 64x128 tile, grid (8,64) = 512 blocks.
// ---------------------------------------------------------------------------
__global__ __launch_bounds__(256) void outproj_mfma_kernel(
    const unsigned short* __restrict__ Ab, const unsigned short* __restrict__ Wot,
    float* __restrict__ out)
{
    __shared__ __align__(16) unsigned char As[8192];
    __shared__ __align__(16) unsigned char Bs[16384];

    const int tid = threadIdx.x, lane = tid & 63, w = tid >> 6;
    const int lr = lane & 15, lg = lane >> 4;
    const int wm = w >> 1, wn = w & 1;
    const int bn = blockIdx.x, bm = blockIdx.y;
    const int m0 = bm * 64, n0 = bn * 128;

    const int chunkR = lane >> 3;
    const int srcOff = 8 * ((lane & 7) ^ chunkR);

    f32x4 acc[2][4] = {};

    for (int k0 = 0; k0 < 1024; k0 += 64) {
        __syncthreads();
        #pragma unroll
        for (int i = 0; i < 6; ++i) {
            const int c = w * 6 + i;
            if (c < 8) {
                const int row = c * 8 + chunkR;
                gload16(Ab + (size_t)(m0 + row) * 1024 + k0 + srcOff, As + c * 1024);
            } else {
                const int row = (c - 8) * 8 + chunkR;
                gload16(Wot + (size_t)(n0 + row) * 1024 + k0 + srcOff,
                        Bs + (c - 8) * 1024);
            }
        }
        __syncthreads();
        #pragma unroll
        for (int kk = 0; kk < 2; ++kk) {
            bf16x8 af[2], bfr[4];
            #pragma unroll
            for (int mf = 0; mf < 2; ++mf) {
                const int row = wm * 32 + mf * 16 + lr;
                af[mf] = *(const bf16x8*)(As + row * 128 +
                          ((kk * 64 + lg * 16) ^ ((row & 7) << 4)));
            }
            #pragma unroll
            for (int nf = 0; nf < 4; ++nf) {
                const int row = wn * 64 + nf * 16 + lr;
                bfr[nf] = *(const bf16x8*)(Bs + row * 128 +
                          ((kk * 64 + lg * 16) ^ ((row & 7) << 4)));
            }
            #pragma unroll
            for (int mf = 0; mf < 2; ++mf)
                #pragma unroll
                for (int nf = 0; nf < 4; ++nf)
                    acc[mf][nf] = MFMA16(af[mf], bfr[nf], acc[mf][nf]);
        }
    }

    #pragma unroll
    for (int nf = 0; nf < 4; ++nf) {
        const int col = n0 + wn * 64 + nf * 16 + lr;
        #pragma unroll
        for (int mf = 0; mf < 2; ++mf) {
            const int mrow = m0 + wm * 32 + mf * 16 + lg * 4;
            #pragma unroll
            for (int r = 0; r < 4; ++r)
                out[(size_t)(mrow + r) * 1024 + col] = acc[mf][nf][r];
        }
    }
}

// ---------------------------------------------------------------------------
extern "C" void kernel_launch(void* const* d_in, const int* in_sizes, int n_in,
                              void* d_out, int out_size, void* d_ws, size_t ws_size,
                              hipStream_t stream)
{
    const float* x     = (const float*)d_in[0];
    const float* sinp  = (const float*)d_in[1];
    const float* cosp  = (const float*)d_in[2];
    const float* maskp = (const float*)d_in[3];
    const float* Wq    = (const float*)d_in[4];
    const float* Wk    = (const float*)d_in[5];
    const float* Wv    = (const float*)d_in[6];
    const float* Wo    = (const float*)d_in[7];

    unsigned short* wsb = (unsigned short*)d_ws;
    unsigned short* xb  = wsb + XB_OFF;
    unsigned short* Wt  = wsb + WT_OFF;
    unsigned short* Wot = wsb + WOT_OFF;
    unsigned short* Qw  = wsb + QB_OFF;
    unsigned short* Kw  = wsb + KB_OFF;
    unsigned short* Vtw = wsb + VTB_OFF;
    unsigned short* Ab  = wsb + AB_OFF;
    float* mbias        = (float*)(wsb + MB_OFF);
    float* out = (float*)d_out;

    prepass_kernel<<<2689, 256, 0, stream>>>(x, Wq, Wk, Wv, Wo, maskp,
                                             xb, Wt, Wot, mbias);
    qkv_mfma_kernel<<<dim3(12, 64), 256, 0, stream>>>(xb, Wt, sinp, cosp,
                                                      Qw, Kw, Vtw);
    attn_kernel<<<dim3(1024), 512, 0, stream>>>(
        Qw, Kw, Vtw, mbias, Ab);
    outproj_mfma_kernel<<<dim3(8, 64), 256, 0, stream>>>(Ab, Wot, out);
}